// Round 13
// baseline (16895.312 us; speedup 1.0000x reference)
//
#include <hip/hip_runtime.h>

#define NB 256
#define NT 8192
#define NI 6
#define NU 64
#define NM 16
#define UNFOLDS 6
#define EPSF 1e-8f
#define LOG2E 1.44269504088896340736f

typedef float v2f __attribute__((ext_vector_type(2)));

__device__ __forceinline__ float fexp2(float x) { return __builtin_amdgcn_exp2f(x); }
__device__ __forceinline__ float frcp(float x)  { return __builtin_amdgcn_rcpf(x); }

// 8-lane all-reduce sum via DPP (lanes grouped 8-aligned within a wave).
template <int CTRL>
__device__ __forceinline__ float dpp_add(float x) {
  int t = __builtin_amdgcn_update_dpp(0, __float_as_int(x), CTRL, 0xF, 0xF, true);
  return x + __int_as_float(t);
}
__device__ __forceinline__ float red8(float x) {
  x = dpp_add<0xB1>(x);   // xor 1 (quad_perm [1,0,3,2])
  x = dpp_add<0x4E>(x);   // xor 2 (quad_perm [2,3,0,1])
  x = dpp_add<0x141>(x);  // -> other quad (row_half_mirror), quad-uniform by then
  return x;
}

// LDS-only barrier: drains lgkmcnt but NOT vmcnt (x-prefetch/output stores stay
// in flight). Register-only ops (exp/rcp/DPP) may still be scheduled across it.
__device__ __forceinline__ void lds_barrier() {
  asm volatile("s_waitcnt lgkmcnt(0)\n\ts_barrier" ::: "memory");
}

// One block = one batch row. 512 threads: thread = (j = tid>>3 dst unit, c = tid&7 src chunk).
// Per lane: 8 synapses as TWO QUADS sharing one rcp each (prefix/suffix recovery);
// {num,den} accumulators packed v2f; cmt*v folded into the seed (off critical path).
// Sensory for step t+1 computed inside step t's unfold phase (cross-step pipeline).
__global__ __launch_bounds__(512, 2) void ltc_kernel(
    const float* __restrict__ x,
    const float* __restrict__ gleak, const float* __restrict__ vleak,
    const float* __restrict__ cm,
    const float* __restrict__ sigma, const float* __restrict__ mu,
    const float* __restrict__ w,     const float* __restrict__ erev,
    const float* __restrict__ ssigma, const float* __restrict__ smu,
    const float* __restrict__ sw_,    const float* __restrict__ serev,
    const float* __restrict__ iw, const float* __restrict__ ib,
    const float* __restrict__ ow_, const float* __restrict__ ob_,
    float* __restrict__ out)
{
  const int tid = threadIdx.x;
  const int b   = blockIdx.x;
  const int j   = tid >> 3;   // dst unit 0..63
  const int c   = tid & 7;    // src chunk 0..7
  const int i0  = c * 8;

  // ---- preload + pre-transform recurrent weights (once per 8192 steps) ----
  // sigmoid((v-mu)*sigma) = 1/(1+exp2(y)), y = fma(v, -sg, mu*sg), sg = sigma*log2e.
  v2f a1p[4], a0p[4], wq[8];
#pragma unroll
  for (int k = 0; k < 8; ++k) {
    const int idx = (i0 + k) * NU + j;
    const float sg = sigma[idx] * LOG2E;
    a1p[k >> 1][k & 1] = -sg;
    a0p[k >> 1][k & 1] = mu[idx] * sg;
    const float wvk = w[idx];
    wq[k] = (v2f){wvk * erev[idx], wvk};   // {w*erev, w}
  }
  // sensory synapse: lane handles src i == c (c >= 6 contributes exactly 0)
  float b1 = 0.f, b0 = 0.f, swv = 0.f, swe = 0.f;
  if (c < NI) {
    const int idx = c * NU + j;
    const float sg = ssigma[idx] * LOG2E;
    b1 = -sg * iw[c];
    b0 = sg * (smu[idx] - ib[c]);
    swv = sw_[idx];
    swe = swv * serev[idx];
  }
  const float gl   = gleak[j];
  const float glvl = gl * vleak[j];
  const float cmt  = cm[j] * (float)UNFOLDS;   // cm / (elapsed/unfolds), elapsed=1
  const float cmt8 = cmt * 0.125f;             // folded through the x8 red8
  const float ow   = (j < NM) ? ow_[j] : 0.f;
  const float ob   = (j < NM) ? ob_[j] : 0.f;

  __shared__ float vbuf[2][NU];
  float v = 0.f;                 // this lane's dst-unit state (replicated across its 8 chunk-lanes)
  if (c == 0) vbuf[0][j] = 0.f;
  __syncthreads();

  const float* xp = x + (size_t)b * NT * NI + (c < NI ? c : 0);
  float* op = out + (size_t)b * NT * NM;

  // sensory -> packed seed {num_base, den_base}/8 (exact; folds through the x8 red8)
  auto sens_seed = [&](float xv) -> v2f {
    const float es   = fexp2(fmaf(xv, b1, b0));
    const float ssig = frcp(1.f + es);
    const float num_s = red8(swe * ssig);
    const float den_s = red8(swv * ssig);
    return (v2f){(glvl + num_s) * 0.125f,
                 (cmt + gl + den_s + EPSF) * 0.125f};
  };

  v2f seedA = sens_seed(xp[0]);     // seed for t=0
  float xv_nxt = xp[NI];            // x at t=1
  v2f seedB;

  // one ODE unfold: read vbuf[p], update, write vbuf[p^1]
  auto unfold_step = [&](int p) {
    // cmt*v folded into the seed BEFORE the ds_read returns (off critical path)
    v2f accA = (v2f){fmaf(cmt8, v, seedA.x), seedA.y};
    v2f accB = (v2f){0.f, 0.f};

    float vv[8];
    *(float4*)&vv[0] = *(const float4*)&vbuf[p][i0];
    *(float4*)&vv[4] = *(const float4*)&vbuf[p][i0 + 4];

#pragma unroll
    for (int h = 0; h < 2; ++h) {            // two quads of 4 synapses
      const int k = 4 * h;
      const v2f ya = (v2f){vv[k], vv[k + 1]} * a1p[2 * h] + a0p[2 * h];
      const v2f yb = (v2f){vv[k + 2], vv[k + 3]} * a1p[2 * h + 1] + a0p[2 * h + 1];
      const float d0 = 1.f + fexp2(ya.x);
      const float d1 = 1.f + fexp2(ya.y);
      const float d2 = 1.f + fexp2(yb.x);
      const float d3 = 1.f + fexp2(yb.y);
      const float d01 = d0 * d1;
      const float d23 = d2 * d3;
      const float r   = frcp(d01 * d23);     // ONE rcp per 4 sigmoids
      const float r01 = r * d23;             // = 1/(d0*d1)
      const float r23 = r * d01;             // = 1/(d2*d3)
      const v2f t01 = wq[k] * d1 + wq[k + 1] * d0;         // pk_mul + pk_fma
      const v2f t23 = wq[k + 2] * d3 + wq[k + 3] * d2;
      accA += t01 * r01;                     // pk_fma
      accB += t23 * r23;
    }
    const v2f acc = accA + accB;
    const float an = red8(acc.x);   // = (cmt*v + num_base + sum(we*s))
    const float ad = red8(acc.y);   // = (den_base + sum(wv*s))
    v = an * frcp(ad);
    if (c == 0) vbuf[p ^ 1][j] = v;
    lds_barrier();
  };

  for (int t = 0; t < NT; ++t) {
    // distance-2 prefetch (stays in flight; barriers are LDS-only)
    const int tn = (t + 2 < NT) ? (t + 2) : (NT - 1);
    const float xf = xp[tn * NI];

    unfold_step(0);
    // pipelined sensory for step t+1: register-only independent trans/DPP work
    seedB = sens_seed(xv_nxt);
    unfold_step(1);
    unfold_step(0);
    unfold_step(1);
    unfold_step(0);
    unfold_step(1);

    // ---- map_outputs: first NM motor neurons ----
    if (c == 0 && j < NM) op[t * NM + j] = fmaf(v, ow, ob);

    seedA = seedB;
    xv_nxt = xf;
  }
}

extern "C" void kernel_launch(void* const* d_in, const int* in_sizes, int n_in,
                              void* d_out, int out_size, void* d_ws, size_t ws_size,
                              hipStream_t stream) {
  (void)in_sizes; (void)n_in; (void)d_ws; (void)ws_size; (void)out_size;
  const float* x      = (const float*)d_in[0];
  const float* gleak  = (const float*)d_in[1];
  const float* vleak  = (const float*)d_in[2];
  const float* cm     = (const float*)d_in[3];
  const float* sigma  = (const float*)d_in[4];
  const float* mu     = (const float*)d_in[5];
  const float* w      = (const float*)d_in[6];
  const float* erev   = (const float*)d_in[7];
  const float* ssig   = (const float*)d_in[8];
  const float* smu    = (const float*)d_in[9];
  const float* sw     = (const float*)d_in[10];
  const float* serev  = (const float*)d_in[11];
  const float* iw     = (const float*)d_in[12];
  const float* ib     = (const float*)d_in[13];
  const float* ow     = (const float*)d_in[14];
  const float* ob     = (const float*)d_in[15];
  float* out = (float*)d_out;

  ltc_kernel<<<dim3(NB), dim3(512), 0, stream>>>(
      x, gleak, vleak, cm, sigma, mu, w, erev,
      ssig, smu, sw, serev, iw, ib, ow, ob, out);
}

// Round 14
// 15767.690 us; speedup vs baseline: 1.0715x; 1.0715x over previous
//
#include <hip/hip_runtime.h>

#define NB 256
#define NT 8192
#define NI 6
#define NU 64
#define NM 16
#define UNFOLDS 6
#define EPSF 1e-8f
#define LOG2E 1.44269504088896340736f

typedef float v2f __attribute__((ext_vector_type(2)));

__device__ __forceinline__ float fexp2(float x) { return __builtin_amdgcn_exp2f(x); }
__device__ __forceinline__ float frcp(float x)  { return __builtin_amdgcn_rcpf(x); }

// 8-lane all-reduce sum via DPP (lanes grouped 8-aligned within a wave).
template <int CTRL>
__device__ __forceinline__ float dpp_add(float x) {
  int t = __builtin_amdgcn_update_dpp(0, __float_as_int(x), CTRL, 0xF, 0xF, true);
  return x + __int_as_float(t);
}
__device__ __forceinline__ float red8(float x) {
  x = dpp_add<0xB1>(x);   // xor 1 (quad_perm [1,0,3,2])
  x = dpp_add<0x4E>(x);   // xor 2 (quad_perm [2,3,0,1])
  x = dpp_add<0x141>(x);  // -> other quad (row_half_mirror), quad-uniform by then
  return x;
}

// LDS-only barrier: drains lgkmcnt but NOT vmcnt (x-prefetch/output stores stay
// in flight). Register-only ops (exp/rcp/DPP) may still be scheduled across it.
__device__ __forceinline__ void lds_barrier() {
  asm volatile("s_waitcnt lgkmcnt(0)\n\ts_barrier" ::: "memory");
}

// One block = one batch row. 512 threads: thread = (j = tid>>3 dst unit, c = tid&7 src chunk).
// Per lane: 8 synapses as 4 pairs sharing one rcp; {num,den} accumulators packed v2f.
// Sensory for step t+1 is computed inside step t's unfold phase (cross-step pipeline).
//
// Structural floor (measured, this session): wall 801 cy/SIMD-unfold =
// issue 521 (trans 338: 8 exp + 4 pair-rcp + 1 den-rcp, irreducible) +
// exposed chain ~280 (barrier->ds_read->exp/rcp->red8->rcp->write->barrier,
// conservation-bound; no co-resident independent work exists at 1 row/CU).
__global__ __launch_bounds__(512, 2) void ltc_kernel(
    const float* __restrict__ x,
    const float* __restrict__ gleak, const float* __restrict__ vleak,
    const float* __restrict__ cm,
    const float* __restrict__ sigma, const float* __restrict__ mu,
    const float* __restrict__ w,     const float* __restrict__ erev,
    const float* __restrict__ ssigma, const float* __restrict__ smu,
    const float* __restrict__ sw_,    const float* __restrict__ serev,
    const float* __restrict__ iw, const float* __restrict__ ib,
    const float* __restrict__ ow_, const float* __restrict__ ob_,
    float* __restrict__ out)
{
  const int tid = threadIdx.x;
  const int b   = blockIdx.x;
  const int j   = tid >> 3;   // dst unit 0..63
  const int c   = tid & 7;    // src chunk 0..7
  const int i0  = c * 8;

  // ---- preload + pre-transform recurrent weights (once per 8192 steps) ----
  // sigmoid((v-mu)*sigma) = 1/(1+exp2(y)), y = fma(v, -sg, mu*sg), sg = sigma*log2e.
  v2f a1p[4], a0p[4], wq[8];
#pragma unroll
  for (int k = 0; k < 8; ++k) {
    const int idx = (i0 + k) * NU + j;
    const float sg = sigma[idx] * LOG2E;
    a1p[k >> 1][k & 1] = -sg;
    a0p[k >> 1][k & 1] = mu[idx] * sg;
    const float wvk = w[idx];
    wq[k] = (v2f){wvk * erev[idx], wvk};   // {w*erev, w}
  }
  // sensory synapse: lane handles src i == c (c >= 6 contributes exactly 0)
  float b1 = 0.f, b0 = 0.f, swv = 0.f, swe = 0.f;
  if (c < NI) {
    const int idx = c * NU + j;
    const float sg = ssigma[idx] * LOG2E;
    b1 = -sg * iw[c];
    b0 = sg * (smu[idx] - ib[c]);
    swv = sw_[idx];
    swe = swv * serev[idx];
  }
  const float gl   = gleak[j];
  const float glvl = gl * vleak[j];
  const float cmt  = cm[j] * (float)UNFOLDS;   // cm / (elapsed/unfolds), elapsed=1
  const float ow   = (j < NM) ? ow_[j] : 0.f;
  const float ob   = (j < NM) ? ob_[j] : 0.f;

  __shared__ float vbuf[2][NU];
  float v = 0.f;                 // this lane's dst-unit state (replicated across its 8 chunk-lanes)
  if (c == 0) vbuf[0][j] = 0.f;
  __syncthreads();

  const float* xp = x + (size_t)b * NT * NI + (c < NI ? c : 0);
  float* op = out + (size_t)b * NT * NM;

  // sensory -> packed seed {num_base, den_base}/8 (exact; folds through the x8 red8)
  auto sens_seed = [&](float xv) -> v2f {
    const float es   = fexp2(fmaf(xv, b1, b0));
    const float ssig = frcp(1.f + es);
    const float num_s = red8(swe * ssig);
    const float den_s = red8(swv * ssig);
    return (v2f){(glvl + num_s) * 0.125f,
                 (cmt + gl + den_s + EPSF) * 0.125f};
  };

  v2f seedA = sens_seed(xp[0]);     // seed for t=0
  float xv_nxt = xp[NI];            // x at t=1 (NT >> 2)
  v2f seedB;

  // one ODE unfold: read vbuf[p], update, write vbuf[p^1]
  auto unfold_step = [&](int p) {
    float vv[8];
    *(float4*)&vv[0] = *(const float4*)&vbuf[p][i0];
    *(float4*)&vv[4] = *(const float4*)&vbuf[p][i0 + 4];
    v2f vp2[4] = { {vv[0], vv[1]}, {vv[2], vv[3]}, {vv[4], vv[5]}, {vv[6], vv[7]} };

    v2f accA = seedA, accB = (v2f){0.f, 0.f};
#pragma unroll
    for (int q = 0; q < 4; ++q) {
      const v2f y = vp2[q] * a1p[q] + a0p[q];        // v_pk_fma_f32
      const float e0 = fexp2(y.x);
      const float e1 = fexp2(y.y);
      const float d0 = 1.f + e0;
      const float d1 = 1.f + e1;
      const float r  = frcp(d0 * d1);                // one rcp per 2 sigmoids
      v2f tq = wq[2 * q] * d1 + wq[2 * q + 1] * d0;  // pk_mul + pk_fma
      if (q & 1) accB += tq * r; else accA += tq * r;
    }
    const v2f acc = accA + accB;
    const float an = red8(acc.x);   // = num_base + sum(we*s)
    const float ad = red8(acc.y);   // = den_base + sum(wv*s)
    v = fmaf(cmt, v, an) * frcp(ad);
    if (c == 0) vbuf[p ^ 1][j] = v;
    lds_barrier();
  };

  for (int t = 0; t < NT; ++t) {
    // distance-2 prefetch (stays in flight; barriers are LDS-only)
    const int tn = (t + 2 < NT) ? (t + 2) : (NT - 1);
    const float xf = xp[tn * NI];

    unfold_step(0);
    // pipelined sensory for step t+1: register-only independent trans/DPP work
    // that fills unfold-phase bubbles and leaves the inter-step serial path
    seedB = sens_seed(xv_nxt);
    unfold_step(1);
    unfold_step(0);
    unfold_step(1);
    unfold_step(0);
    unfold_step(1);

    // ---- map_outputs: first NM motor neurons ----
    if (c == 0 && j < NM) op[t * NM + j] = fmaf(v, ow, ob);

    seedA = seedB;
    xv_nxt = xf;
  }
}

extern "C" void kernel_launch(void* const* d_in, const int* in_sizes, int n_in,
                              void* d_out, int out_size, void* d_ws, size_t ws_size,
                              hipStream_t stream) {
  (void)in_sizes; (void)n_in; (void)d_ws; (void)ws_size; (void)out_size;
  const float* x      = (const float*)d_in[0];
  const float* gleak  = (const float*)d_in[1];
  const float* vleak  = (const float*)d_in[2];
  const float* cm     = (const float*)d_in[3];
  const float* sigma  = (const float*)d_in[4];
  const float* mu     = (const float*)d_in[5];
  const float* w      = (const float*)d_in[6];
  const float* erev   = (const float*)d_in[7];
  const float* ssig   = (const float*)d_in[8];
  const float* smu    = (const float*)d_in[9];
  const float* sw     = (const float*)d_in[10];
  const float* serev  = (const float*)d_in[11];
  const float* iw     = (const float*)d_in[12];
  const float* ib     = (const float*)d_in[13];
  const float* ow     = (const float*)d_in[14];
  const float* ob     = (const float*)d_in[15];
  float* out = (float*)d_out;

  ltc_kernel<<<dim3(NB), dim3(512), 0, stream>>>(
      x, gleak, vleak, cm, sigma, mu, w, erev,
      ssig, smu, sw, serev, iw, ib, ow, ob, out);
}

// Round 15
// 15689.095 us; speedup vs baseline: 1.0769x; 1.0050x over previous
//
#include <hip/hip_runtime.h>

#define NB 256
#define NT 8192
#define NI 6
#define NU 64
#define NM 16
#define UNFOLDS 6
#define EPSF 1e-8f
#define LOG2E 1.44269504088896340736f

typedef float v2f __attribute__((ext_vector_type(2)));

__device__ __forceinline__ float fexp2(float x) { return __builtin_amdgcn_exp2f(x); }
__device__ __forceinline__ float frcp(float x)  { return __builtin_amdgcn_rcpf(x); }

// 4-lane all-reduce sum via DPP (chunk lanes are quad-aligned: tid = j*4+c).
template <int CTRL>
__device__ __forceinline__ float dpp_add(float x) {
  int t = __builtin_amdgcn_update_dpp(0, __float_as_int(x), CTRL, 0xF, 0xF, true);
  return x + __int_as_float(t);
}
__device__ __forceinline__ float red4(float x) {
  x = dpp_add<0xB1>(x);   // xor 1 (quad_perm [1,0,3,2])
  x = dpp_add<0x4E>(x);   // xor 2 (quad_perm [2,3,0,1])
  return x;
}

// LDS-only barrier: drains lgkmcnt but NOT vmcnt (x-prefetch/output stores stay
// in flight). Register-only ops (exp/rcp/DPP) may still be scheduled across it.
__device__ __forceinline__ void lds_barrier() {
  asm volatile("s_waitcnt lgkmcnt(0)\n\ts_barrier" ::: "memory");
}

// One block = one batch row. 256 threads: thread = (j = tid>>2 dst unit, c = tid&3 chunk).
// Lane (j,c) handles 16 synapses (src i in [16c,16c+16)). 4 waves/block = ONE wave/SIMD:
// issue work is not replicated across lockstep waves (R3/R12 model: wall =
// waves/SIMD * issue/wave + ~280cy chain gap, waves never fill each other's gap).
// Per lane: 16 synapses as 8 pairs sharing one rcp; {num,den} accumulators packed v2f.
// Sensory for step t+1 computed inside step t's unfold phase (cross-step pipeline).
__global__ __launch_bounds__(256, 1) void ltc_kernel(
    const float* __restrict__ x,
    const float* __restrict__ gleak, const float* __restrict__ vleak,
    const float* __restrict__ cm,
    const float* __restrict__ sigma, const float* __restrict__ mu,
    const float* __restrict__ w,     const float* __restrict__ erev,
    const float* __restrict__ ssigma, const float* __restrict__ smu,
    const float* __restrict__ sw_,    const float* __restrict__ serev,
    const float* __restrict__ iw, const float* __restrict__ ib,
    const float* __restrict__ ow_, const float* __restrict__ ob_,
    float* __restrict__ out)
{
  const int tid = threadIdx.x;
  const int b   = blockIdx.x;
  const int j   = tid >> 2;   // dst unit 0..63
  const int c   = tid & 3;    // src chunk 0..3
  const int i0  = c * 16;

  // ---- preload + pre-transform recurrent weights (once per 8192 steps) ----
  // sigmoid((v-mu)*sigma) = 1/(1+exp2(y)), y = fma(v, -sg, mu*sg), sg = sigma*log2e.
  v2f a1p[8], a0p[8], wq[16];
#pragma unroll
  for (int k = 0; k < 16; ++k) {
    const int idx = (i0 + k) * NU + j;
    const float sg = sigma[idx] * LOG2E;
    a1p[k >> 1][k & 1] = -sg;
    a0p[k >> 1][k & 1] = mu[idx] * sg;
    const float wvk = w[idx];
    wq[k] = (v2f){wvk * erev[idx], wvk};   // {w*erev, w}
  }
  // sensory synapses: lane c handles src i = c, and i = c+4 when c < 2
  // (NI=6 srcs over 4 chunks; c>=2 second slot is zero-weighted and harmless)
  float b1a = 0.f, b0a = 0.f, swva = 0.f, swea = 0.f;
  float b1b = 0.f, b0b = 0.f, swvb = 0.f, sweb = 0.f;
  {
    const int ia = c;                    // always < NI (c in [0,4))
    const int idxa = ia * NU + j;
    const float sga = ssigma[idxa] * LOG2E;
    b1a = -sga * iw[ia];
    b0a = sga * (smu[idxa] - ib[ia]);
    swva = sw_[idxa];
    swea = swva * serev[idxa];
    if (c < 2) {
      const int ib2 = c + 4;
      const int idxb = ib2 * NU + j;
      const float sgb = ssigma[idxb] * LOG2E;
      b1b = -sgb * iw[ib2];
      b0b = sgb * (smu[idxb] - ib[ib2]);
      swvb = sw_[idxb];
      sweb = swvb * serev[idxb];
    }
  }
  const float gl   = gleak[j];
  const float glvl = gl * vleak[j];
  const float cmt  = cm[j] * (float)UNFOLDS;   // cm / (elapsed/unfolds), elapsed=1
  const float ow   = (j < NM) ? ow_[j] : 0.f;
  const float ob   = (j < NM) ? ob_[j] : 0.f;

  __shared__ float vbuf[2][NU];
  float v = 0.f;                 // this lane's dst-unit state (replicated across its 4 chunk-lanes)
  if (c == 0) vbuf[0][j] = 0.f;
  __syncthreads();

  const float* xpA = x + (size_t)b * NT * NI + c;              // valid for all c
  const float* xpB = x + (size_t)b * NT * NI + ((c < 2) ? (c + 4) : 0);
  float* op = out + (size_t)b * NT * NM;

  // sensory -> packed seed {num_base, den_base}/4 (exact; folds through the x4 red4)
  auto sens_seed = [&](float xa, float xb) -> v2f {
    const float e0 = fexp2(fmaf(xa, b1a, b0a));
    const float e1 = fexp2(fmaf(xb, b1b, b0b));
    const float d0 = 1.f + e0;
    const float d1 = 1.f + e1;
    const float r  = frcp(d0 * d1);        // one rcp for both sensory sigmoids
    const float s0 = d1 * r;
    const float s1 = d0 * r;
    const float num_s = red4(fmaf(swea, s0, sweb * s1));
    const float den_s = red4(fmaf(swva, s0, swvb * s1));
    return (v2f){(glvl + num_s) * 0.25f,
                 (cmt + gl + den_s + EPSF) * 0.25f};
  };

  v2f seedA = sens_seed(xpA[0], xpB[0]);   // seed for t=0
  float xvA_nxt = xpA[NI];                 // x at t=1
  float xvB_nxt = xpB[NI];
  v2f seedB;

  // one ODE unfold: read vbuf[p], update, write vbuf[p^1]
  auto unfold_step = [&](int p) {
    float vv[16];
    *(float4*)&vv[0]  = *(const float4*)&vbuf[p][i0];
    *(float4*)&vv[4]  = *(const float4*)&vbuf[p][i0 + 4];
    *(float4*)&vv[8]  = *(const float4*)&vbuf[p][i0 + 8];
    *(float4*)&vv[12] = *(const float4*)&vbuf[p][i0 + 12];

    v2f accA = seedA, accB = (v2f){0.f, 0.f};
#pragma unroll
    for (int q = 0; q < 8; ++q) {          // 8 pairs of synapses
      const v2f y = (v2f){vv[2 * q], vv[2 * q + 1]} * a1p[q] + a0p[q];  // v_pk_fma_f32
      const float e0 = fexp2(y.x);
      const float e1 = fexp2(y.y);
      const float d0 = 1.f + e0;
      const float d1 = 1.f + e1;
      const float r  = frcp(d0 * d1);                // one rcp per 2 sigmoids
      v2f tq = wq[2 * q] * d1 + wq[2 * q + 1] * d0;  // pk_mul + pk_fma
      if (q & 1) accB += tq * r; else accA += tq * r;
    }
    const v2f acc = accA + accB;
    const float an = red4(acc.x);   // = num_base + sum(we*s)
    const float ad = red4(acc.y);   // = den_base + sum(wv*s)
    v = fmaf(cmt, v, an) * frcp(ad);
    if (c == 0) vbuf[p ^ 1][j] = v;
    lds_barrier();
  };

  for (int t = 0; t < NT; ++t) {
    // distance-2 prefetch (stays in flight; barriers are LDS-only)
    const int tn = (t + 2 < NT) ? (t + 2) : (NT - 1);
    const float xfA = xpA[tn * NI];
    const float xfB = xpB[tn * NI];

    unfold_step(0);
    // pipelined sensory for step t+1: register-only independent trans/DPP work
    seedB = sens_seed(xvA_nxt, xvB_nxt);
    unfold_step(1);
    unfold_step(0);
    unfold_step(1);
    unfold_step(0);
    unfold_step(1);

    // ---- map_outputs: first NM motor neurons ----
    if (c == 0 && j < NM) op[t * NM + j] = fmaf(v, ow, ob);

    seedA = seedB;
    xvA_nxt = xfA;
    xvB_nxt = xfB;
  }
}

extern "C" void kernel_launch(void* const* d_in, const int* in_sizes, int n_in,
                              void* d_out, int out_size, void* d_ws, size_t ws_size,
                              hipStream_t stream) {
  (void)in_sizes; (void)n_in; (void)d_ws; (void)ws_size; (void)out_size;
  const float* x      = (const float*)d_in[0];
  const float* gleak  = (const float*)d_in[1];
  const float* vleak  = (const float*)d_in[2];
  const float* cm     = (const float*)d_in[3];
  const float* sigma  = (const float*)d_in[4];
  const float* mu     = (const float*)d_in[5];
  const float* w      = (const float*)d_in[6];
  const float* erev   = (const float*)d_in[7];
  const float* ssig   = (const float*)d_in[8];
  const float* smu    = (const float*)d_in[9];
  const float* sw     = (const float*)d_in[10];
  const float* serev  = (const float*)d_in[11];
  const float* iw     = (const float*)d_in[12];
  const float* ib     = (const float*)d_in[13];
  const float* ow     = (const float*)d_in[14];
  const float* ob     = (const float*)d_in[15];
  float* out = (float*)d_out;

  ltc_kernel<<<dim3(NB), dim3(256), 0, stream>>>(
      x, gleak, vleak, cm, sigma, mu, w, erev,
      ssig, smu, sw, serev, iw, ib, ow, ob, out);
}